// Round 7
// baseline (1879.933 us; speedup 1.0000x reference)
//
#include <hip/hip_runtime.h>
#include <hip/hip_bf16.h>

// ---------------- output layout constants (floats) ----------------
constexpr size_t OFF_W1 = 1;
constexpr size_t OFF_B1 = OFF_W1 + (size_t)1024*32768;
constexpr size_t OFF_W2 = OFF_B1 + (size_t)1024*256;
constexpr size_t OFF_B2 = OFF_W2 + (size_t)1024*65536;
constexpr size_t OFF_W3 = OFF_B2 + (size_t)1024*256;
constexpr size_t OFF_B3 = OFF_W3 + (size_t)1024*32768;

// ================= 256-thread fused-MLP blocks (proven; prep/scanrel) =================
__device__ __forceinline__ void layer_n128(
    const float* __restrict__ W, const float* __restrict__ bias, int K,
    const float* __restrict__ x, int xs, float* __restrict__ y, int ys, int relu,
    int rows, int t)
{
    const int c4 = (t & 31) * 4;
    int r = t >> 5; if (rows == 4) r &= 3;
    float4 a = bias ? *(const float4*)&bias[c4] : make_float4(0.f,0.f,0.f,0.f);
    const float* xr = x + r * xs;
    for (int k = 0; k < K; ++k) {
        float4 w = *(const float4*)&W[(size_t)k*128 + c4];
        float xa = xr[k];
        a.x = fmaf(w.x, xa, a.x); a.y = fmaf(w.y, xa, a.y);
        a.z = fmaf(w.z, xa, a.z); a.w = fmaf(w.w, xa, a.w);
    }
    if (relu) {
        a.x=fmaxf(a.x,0.f); a.y=fmaxf(a.y,0.f); a.z=fmaxf(a.z,0.f); a.w=fmaxf(a.w,0.f);
    }
    *(float4*)&y[r*ys + c4] = a;
}

// N=256, 8 rows, 512 threads (1 row x 4 cols per thread)
__device__ __forceinline__ void layer_n256_512(
    const float* __restrict__ W, const float* __restrict__ bias, int K,
    const float* __restrict__ x, int xs, float* __restrict__ y, int relu, int t)
{
    const int c4 = (t & 63) * 4;
    const int r = t >> 6;                 // 0..7
    float4 a = bias ? *(const float4*)&bias[c4] : make_float4(0.f,0.f,0.f,0.f);
    const float* xr = x + r * xs;
    for (int k = 0; k < K; ++k) {
        float4 w = *(const float4*)&W[(size_t)k*256 + c4];
        float xa = xr[k];
        a.x = fmaf(w.x, xa, a.x); a.y = fmaf(w.y, xa, a.y);
        a.z = fmaf(w.z, xa, a.z); a.w = fmaf(w.w, xa, a.w);
    }
    if (relu) {
        a.x=fmaxf(a.x,0.f); a.y=fmaxf(a.y,0.f); a.z=fmaxf(a.z,0.f); a.w=fmaxf(a.w,0.f);
    }
    *(float4*)&y[r*256 + c4] = a;
}

// ================= 512-thread K-split blocks (mega) =================
// N=256, 4 rows, 2-way K-split. part: >=2048 floats. Two barriers inside.
__device__ __forceinline__ void layer_ks2_n256(
    const float* __restrict__ W, const float* __restrict__ bias, int K,
    const float* __restrict__ x, int xs, float* __restrict__ y, int relu,
    const float* __restrict__ mask, float* __restrict__ part, int t)
{
    const int g = t >> 8;                 // 0..1
    const int tt = t & 255;
    const int r = tt >> 6, c4 = (tt & 63) * 4;
    const int kh = K >> 1;
    const int kb = g * kh;
    float4 a = make_float4(0.f,0.f,0.f,0.f);
    const float* xr = x + r * xs;
    for (int k = kb; k < kb + kh; ++k) {
        float4 w = *(const float4*)&W[(size_t)k*256 + c4];
        float xa = xr[k];
        a.x = fmaf(w.x, xa, a.x); a.y = fmaf(w.y, xa, a.y);
        a.z = fmaf(w.z, xa, a.z); a.w = fmaf(w.w, xa, a.w);
    }
    *(float4*)&part[g*1024 + tt*4] = a;
    __syncthreads();
    if (g == 0) {
        float4 p0 = *(const float4*)&part[tt*4];
        float4 p1 = *(const float4*)&part[1024 + tt*4];
        float4 o;
        o.x = p0.x + p1.x; o.y = p0.y + p1.y; o.z = p0.z + p1.z; o.w = p0.w + p1.w;
        if (bias) {
            float4 b = *(const float4*)&bias[c4];
            o.x += b.x; o.y += b.y; o.z += b.z; o.w += b.w;
        }
        if (relu) {
            o.x=fmaxf(o.x,0.f); o.y=fmaxf(o.y,0.f); o.z=fmaxf(o.z,0.f); o.w=fmaxf(o.w,0.f);
        }
        if (mask) {
            float4 m = *(const float4*)&mask[r*256 + c4];
            o.x = (m.x > 0.f) ? o.x : 0.f; o.y = (m.y > 0.f) ? o.y : 0.f;
            o.z = (m.z > 0.f) ? o.z : 0.f; o.w = (m.w > 0.f) ? o.w : 0.f;
        }
        *(float4*)&y[r*256 + c4] = o;
    }
    __syncthreads();
}

// N=128, 4 rows, 4-way K-split. part: >=2048 floats.
__device__ __forceinline__ void layer_ks4_n128(
    const float* __restrict__ W, const float* __restrict__ bias, int K,
    const float* __restrict__ x, int xs, float* __restrict__ y, int ys, int relu,
    float* __restrict__ part, int t)
{
    const int g = t >> 7;                 // 0..3
    const int tt = t & 127;
    const int r = tt >> 5, c4 = (tt & 31) * 4;
    const int kq = K >> 2;
    const int kb = g * kq;
    float4 a = make_float4(0.f,0.f,0.f,0.f);
    const float* xr = x + r * xs;
    for (int k = kb; k < kb + kq; ++k) {
        float4 w = *(const float4*)&W[(size_t)k*128 + c4];
        float xa = xr[k];
        a.x = fmaf(w.x, xa, a.x); a.y = fmaf(w.y, xa, a.y);
        a.z = fmaf(w.z, xa, a.z); a.w = fmaf(w.w, xa, a.w);
    }
    *(float4*)&part[g*512 + tt*4] = a;
    __syncthreads();
    if (g == 0) {
        float4 p0 = *(const float4*)&part[tt*4];
        float4 p1 = *(const float4*)&part[512 + tt*4];
        float4 p2 = *(const float4*)&part[1024 + tt*4];
        float4 p3 = *(const float4*)&part[1536 + tt*4];
        float4 o;
        o.x = (p0.x+p1.x) + (p2.x+p3.x); o.y = (p0.y+p1.y) + (p2.y+p3.y);
        o.z = (p0.z+p1.z) + (p2.z+p3.z); o.w = (p0.w+p1.w) + (p2.w+p3.w);
        if (bias) {
            float4 b = *(const float4*)&bias[c4];
            o.x += b.x; o.y += b.y; o.z += b.z; o.w += b.w;
        }
        if (relu) {
            o.x=fmaxf(o.x,0.f); o.y=fmaxf(o.y,0.f); o.z=fmaxf(o.z,0.f); o.w=fmaxf(o.w,0.f);
        }
        *(float4*)&y[r*ys + c4] = o;
    }
    __syncthreads();
}

// dual-source N=128 proj (virtual K=256: rows 0..127 of W x xA, 128..255 x xB), 4-way split
__device__ __forceinline__ void layer_ks4_n128_dual(
    const float* __restrict__ W,
    const float* __restrict__ xA, const float* __restrict__ xB,
    float* __restrict__ y, float* __restrict__ part, int t)
{
    const int g = t >> 7;                 // 0..3
    const int tt = t & 127;
    const int r = tt >> 5, c4 = (tt & 31) * 4;
    const float* src = (g < 2) ? xA : xB;
    const int kb = (g & 1) * 64;          // offset within source
    const int wb = g * 64;                // W row base
    float4 a = make_float4(0.f,0.f,0.f,0.f);
    const float* xr = src + r * 128;
    for (int k = 0; k < 64; ++k) {
        float4 w = *(const float4*)&W[(size_t)(wb + k)*128 + c4];
        float xa = xr[kb + k];
        a.x = fmaf(w.x, xa, a.x); a.y = fmaf(w.y, xa, a.y);
        a.z = fmaf(w.z, xa, a.z); a.w = fmaf(w.w, xa, a.w);
    }
    *(float4*)&part[g*512 + tt*4] = a;
    __syncthreads();
    if (g == 0) {
        float4 p0 = *(const float4*)&part[tt*4];
        float4 p1 = *(const float4*)&part[512 + tt*4];
        float4 p2 = *(const float4*)&part[1024 + tt*4];
        float4 p3 = *(const float4*)&part[1536 + tt*4];
        float4 o;
        o.x = (p0.x+p1.x) + (p2.x+p3.x); o.y = (p0.y+p1.y) + (p2.y+p3.y);
        o.z = (p0.z+p1.z) + (p2.z+p3.z); o.w = (p0.w+p1.w) + (p2.w+p3.w);
        *(float4*)&y[r*128 + c4] = o;
    }
    __syncthreads();
}

// 512-thread block-sum commit. red: >=8 floats.
__device__ __forceinline__ void block_mse_commit512(float s, float scale,
                                                    float* __restrict__ accum,
                                                    float* __restrict__ red, int t)
{
    #pragma unroll
    for (int off = 32; off > 0; off >>= 1) s += __shfl_down(s, off, 64);
    if ((t & 63) == 0) red[t >> 6] = s;
    __syncthreads();
    if (t == 0) {
        float tot = ((red[0]+red[1]) + (red[2]+red[3])) + ((red[4]+red[5]) + (red[6]+red[7]));
        atomicAdd(accum, tot * scale);
    }
}

// decoder-MSE (512 thr): (ret[:,128:] @ dec_w + dec_b) vs sensory, 4 rows
__device__ __forceinline__ void dec_mse512(
    const float* __restrict__ ret,
    const float* __restrict__ sensory, int row0,
    const float* __restrict__ dec_w, const float* __restrict__ dec_b,
    float* __restrict__ accum, float* __restrict__ red, int t)
{
    const int c4 = (t & 127) * 4;
    const int rb = t >> 7;                // 0..3
    float4 a = *(const float4*)&dec_b[c4];
    const float* x0 = ret + rb*256 + 128;
    for (int k = 0; k < 128; ++k) {
        float4 w = *(const float4*)&dec_w[(size_t)k*512 + c4];
        float xa = x0[k];
        a.x = fmaf(w.x, xa, a.x); a.y = fmaf(w.y, xa, a.y);
        a.z = fmaf(w.z, xa, a.z); a.w = fmaf(w.w, xa, a.w);
    }
    float4 s0 = *(const float4*)&sensory[(size_t)(row0+rb)*512 + c4];
    float dx = a.x-s0.x, dy = a.y-s0.y, dz = a.z-s0.z, dw = a.w-s0.w;
    float s = dx*dx + dy*dy + dz*dz + dw*dw;
    block_mse_commit512(s, 1.f/524288.f, accum, red, t);
}

// ================= launch 1: prep (unchanged, proven) ====
__global__ __launch_bounds__(256) void prep_kernel(
    const float* __restrict__ tW3,
    const float* __restrict__ mW2, const float* __restrict__ mW3,
    const float* __restrict__ actions,
    const float* __restrict__ tW1, const float* __restrict__ tb1,
    const float* __restrict__ tW2, const float* __restrict__ tb2,
    const float* __restrict__ sensory,
    const float* __restrict__ enc_w, const float* __restrict__ enc_b,
    float* __restrict__ tW3T, float* __restrict__ T2, float* __restrict__ T3,
    float* __restrict__ acc, float* __restrict__ a2, float* __restrict__ encoded)
{
    __shared__ float smem[64*129];
    const int t = threadIdx.x;
    const int bid = blockIdx.x;
    if (bid < 256) {
        const int k = bid >> 1, i0 = (bid & 1) * 64;
        const size_t base = (size_t)k << 14;
        for (int l = t; l < 8192; l += 256) {
            int ii = l >> 7, jj = l & 127;
            smem[ii*129 + jj] = tW3[base + (size_t)(i0+ii)*128 + jj];
        }
        __syncthreads();
        for (int l = t; l < 8192; l += 256) {
            int jj = l >> 6, ii = l & 63;
            tW3T[base + (size_t)jj*128 + i0 + ii] = smem[ii*129 + jj];
        }
    } else if (bid < 512) {
        const int c = bid - 256;
        T2[(size_t)c*256 + t] = mW2[(size_t)t*256 + c];
    } else if (bid < 640) {
        const int c = bid - 512;
        T3[(size_t)c*256 + t] = mW3[(size_t)t*128 + c];
    } else if (bid == 640) {
        if (t < 16) acc[t] = 0.f;
    } else if (bid < 769) {
        float* bufAct = smem;            // 256
        float* ping   = smem + 256;      // 1024
        float* pong   = smem + 1280;     // 1024
        const int row0 = (bid - 641) * 8;
        if (t < 64) {
            int r = t >> 3, c4 = (t & 7) * 4;
            *(float4*)&bufAct[r*32 + c4] =
                *(const float4*)&actions[(size_t)(row0 + r)*32 + c4];
        }
        __syncthreads();
        layer_n128(tW1, tb1, 32, bufAct, 32, ping, 128, 1, 8, t);
        __syncthreads();
        layer_n128(tW2, tb2, 128, ping, 128, pong, 128, 1, 8, t);
        __syncthreads();
        {
            int r = t >> 5, c4 = (t & 31) * 4;
            *(float4*)&a2[(size_t)(row0 + r)*128 + c4] = *(const float4*)&pong[r*128 + c4];
        }
    } else {
        // encoder: sensory(1024x512) @ enc_w(512x128) + enc_b -> encoded
        const int q = bid - 769;              // 0..31
        const int m0 = (q & 15) * 64, n0 = (q >> 4) * 64;
        float (*As)[65] = (float(*)[65])smem;
        float (*Ws)[65] = (float(*)[65])(smem + 16*65);
        const int tx = t & 15, ty = t >> 4;
        float a4[4][4] = {};
        for (int k0 = 0; k0 < 512; k0 += 16) {
            for (int l = t; l < 1024; l += 256) {
                int mm = l >> 4, kk = l & 15;
                As[kk][mm] = sensory[(size_t)(m0+mm)*512 + k0 + kk];
            }
            for (int l = t; l < 1024; l += 256) {
                int kk = l >> 6, nn = l & 63;
                Ws[kk][nn] = enc_w[(size_t)(k0+kk)*128 + n0 + nn];
            }
            __syncthreads();
            #pragma unroll
            for (int kk = 0; kk < 16; ++kk) {
                float a[4], b[4];
                #pragma unroll
                for (int i=0;i<4;i++) a[i] = As[kk][ty*4+i];
                #pragma unroll
                for (int j=0;j<4;j++) b[j] = Ws[kk][tx*4+j];
                #pragma unroll
                for (int i=0;i<4;i++)
                    #pragma unroll
                    for (int j=0;j<4;j++)
                        a4[i][j] = fmaf(a[i], b[j], a4[i][j]);
            }
            __syncthreads();
        }
        #pragma unroll
        for (int i=0;i<4;i++){
            int gm = m0 + ty*4 + i;
            #pragma unroll
            for (int j=0;j<4;j++){
                int gn = n0 + tx*4 + j;
                encoded[(size_t)gm*128 + gn] = a4[i][j] + enc_b[gn];
            }
        }
    }
}

// ====== launch 2: K=128 GEMM, 32x256 tiles (unchanged, proven) ======
__global__ __launch_bounds__(256) void gemm_k128_kernel(
    const float* __restrict__ A, int lda, const float* __restrict__ W,
    const float* __restrict__ bias, float* __restrict__ C, int N)
{
    __shared__ float As[128*36];
    const int t = threadIdx.x;
    const int m0 = blockIdx.x * 32, n0 = blockIdx.y * 256;
    for (int l = t; l < 4096; l += 256) {
        int r = l >> 7, k = l & 127;
        As[k*36 + r] = A[(size_t)(m0 + r)*lda + k];
    }
    __syncthreads();
    const int c4 = (t & 63) * 4;
    const int r0 = (t >> 6) * 8;
    float4 bv;
    {   // bias stored transposed: bias[(n&127)*128 + (n>>7)]
        const int n = n0 + c4;
        const int j = n >> 7, i = n & 127;
        bv.x = bias[(size_t)(i+0)*128 + j];
        bv.y = bias[(size_t)(i+1)*128 + j];
        bv.z = bias[(size_t)(i+2)*128 + j];
        bv.w = bias[(size_t)(i+3)*128 + j];
    }
    float4 acc[8];
    #pragma unroll
    for (int i = 0; i < 8; ++i) acc[i] = bv;
    const float* Wp = W + (size_t)n0 + c4;
    #pragma unroll 4
    for (int k = 0; k < 128; ++k) {
        float4 w = *(const float4*)&Wp[(size_t)k*N];
        float a[8];
        *(float4*)&a[0] = *(const float4*)&As[k*36 + r0];
        *(float4*)&a[4] = *(const float4*)&As[k*36 + r0 + 4];
        #pragma unroll
        for (int i = 0; i < 8; ++i) {
            acc[i].x = fmaf(w.x, a[i], acc[i].x);
            acc[i].y = fmaf(w.y, a[i], acc[i].y);
            acc[i].z = fmaf(w.z, a[i], acc[i].z);
            acc[i].w = fmaf(w.w, a[i], acc[i].w);
        }
    }
    #pragma unroll
    for (int i = 0; i < 8; ++i)
        *(float4*)&C[(size_t)(m0 + r0 + i)*N + n0 + c4] = acc[i];
}

// ================= launch 3: scan (blocks 0..7, proven) + relational retrieve (8..135,
//                  N=256 layers now use all 512 threads) ======
__global__ __launch_bounds__(512) void scanrel_kernel(
    const float* __restrict__ transT,
    const float* __restrict__ init_hidden,
    float* __restrict__ structural,
    const float* __restrict__ encoded,
    const float* __restrict__ qw,
    const float* __restrict__ mW1, const float* __restrict__ mb1,
    const float* __restrict__ mW2, const float* __restrict__ mb2,
    const float* __restrict__ mW3, const float* __restrict__ mb3,
    const float* __restrict__ oW1, const float* __restrict__ ob1,
    const float* __restrict__ oW2, const float* __restrict__ ob2,
    const float* __restrict__ oW3, const float* __restrict__ ob3,
    float* __restrict__ out2)
{
    __shared__ float smem[5120];
    const int tid = threadIdx.x;
    if (blockIdx.x < 8) {
        float* h  = smem;        // 128
        float* ws = smem + 128;  // 8
        const int b = blockIdx.x;
        const int j = tid >> 2, p = tid & 3;
        const int i0 = p * 32;

        if (tid < 32) {
            float4 v = *(const float4*)&init_hidden[tid*4];
            float ss = v.x*v.x + v.y*v.y + v.z*v.z + v.w*v.w;
            ss += __shfl_xor(ss, 16); ss += __shfl_xor(ss, 8); ss += __shfl_xor(ss, 4);
            ss += __shfl_xor(ss, 2);  ss += __shfl_xor(ss, 1);
            float inv = 1.f / fmaxf(sqrtf(ss), 1e-12f);
            v.x *= inv; v.y *= inv; v.z *= inv; v.w *= inv;
            *(float4*)&h[tid*4] = v;
        }
        __syncthreads();

        const size_t bbase = ((size_t)b) << 21;
        const int lane_off = j*128 + i0;
        float4 cur[8], nxt[8];
        {
            const float* T0 = transT + bbase + lane_off;
            #pragma unroll
            for (int r = 0; r < 8; ++r) cur[r] = *(const float4*)&T0[r*4];
        }
        for (int t = 0; t < 128; ++t) {
            const int tn = (t < 127) ? t + 1 : 127;
            const float* Tn = transT + bbase + ((size_t)tn << 14) + lane_off;
            #pragma unroll
            for (int r = 0; r < 8; ++r) nxt[r] = *(const float4*)&Tn[r*4];

            float4 a = make_float4(0.f, 0.f, 0.f, 0.f);
            #pragma unroll
            for (int r = 0; r < 8; ++r) {
                float4 hv = *(const float4*)&h[i0 + r*4];
                a.x = fmaf(hv.x, cur[r].x, a.x);
                a.y = fmaf(hv.y, cur[r].y, a.y);
                a.z = fmaf(hv.z, cur[r].z, a.z);
                a.w = fmaf(hv.w, cur[r].w, a.w);
            }
            float s = (a.x + a.y) + (a.z + a.w);
            s += __shfl_xor(s, 1);
            s += __shfl_xor(s, 2);
            float v = fmaxf(s, 0.f);
            float q = v * v;
            q += __shfl_xor(q, 4);  q += __shfl_xor(q, 8);
            q += __shfl_xor(q, 16); q += __shfl_xor(q, 32);
            if ((tid & 63) == 0) ws[tid >> 6] = q;
            __syncthreads();
            float ss = ((ws[0]+ws[1]) + (ws[2]+ws[3])) + ((ws[4]+ws[5]) + (ws[6]+ws[7]));
            float inv = 1.f / fmaxf(sqrtf(ss), 1e-12f);
            float hv = v * inv;
            __syncthreads();
            if (p == 0) h[j] = hv;
            else if (p == 1) structural[(((size_t)(b*128 + t)) << 7) + j] = hv;
            __syncthreads();
            #pragma unroll
            for (int r = 0; r < 8; ++r) cur[r] = nxt[r];
        }
    } else {
        float* bufB = smem;           // 1024
        float* ping = smem + 1024;    // 2048
        float* pong = smem + 3072;    // 2048
        const int row0 = (blockIdx.x - 8) * 8;
        const int t = tid;
        if (t < 256) {
            int r = t >> 5, k4 = (t & 31) * 4;
            *(float4*)&bufB[r*128 + k4] =
                *(const float4*)&encoded[(size_t)(row0 + r)*128 + k4];
        }
        __syncthreads();
        if (t < 256) layer_n128(qw + (size_t)128*128, nullptr, 128, bufB, 128, ping, 128, 0, 8, t);
        __syncthreads();
        layer_n256_512(mW1, mb1, 128, ping, 128, pong, 1, t);
        __syncthreads();
        layer_n256_512(mW2, mb2, 256, pong, 256, ping, 1, t);
        __syncthreads();
        if (t < 256) layer_n128(mW3, mb3, 256, ping, 256, pong, 128, 0, 8, t);
        __syncthreads();
        layer_n256_512(oW1, ob1, 128, pong, 128, ping, 1, t);
        __syncthreads();
        layer_n256_512(oW2, ob2, 256, ping, 256, pong, 1, t);
        __syncthreads();
        layer_n256_512(oW3, ob3, 256, pong, 256, ping, 0, t);
        __syncthreads();
        {
            int r = t >> 6, c = (t & 63) * 4;
            *(float4*)&out2[(size_t)(row0+r)*256 + c] = *(const float4*)&ping[r*256 + c];
        }
    }
}

// ====== launch 4: MEGA v2 — 512 threads, K-split layers (8 waves/CU) ======
__global__ __launch_bounds__(512) void mega_kernel(
    const float* __restrict__ structural, const float* __restrict__ encoded,
    const float* __restrict__ out2, const float* __restrict__ sensory,
    const float* __restrict__ ratio_p,
    const float* __restrict__ qw,
    const float* __restrict__ mW1, const float* __restrict__ mb1,
    const float* __restrict__ mW2, const float* __restrict__ mb2,
    const float* __restrict__ mW3, const float* __restrict__ mb3,
    const float* __restrict__ oW1, const float* __restrict__ ob1,
    const float* __restrict__ oW2, const float* __restrict__ ob2,
    const float* __restrict__ oW3, const float* __restrict__ ob3,
    const float* __restrict__ sW1, const float* __restrict__ sb1,
    const float* __restrict__ sW2, const float* __restrict__ sb2,
    const float* __restrict__ sW3, const float* __restrict__ sb3,
    const float* __restrict__ k_w, const float* __restrict__ v_w,
    const float* __restrict__ T2, const float* __restrict__ T3,
    const float* __restrict__ dec_w, const float* __restrict__ dec_b,
    float* __restrict__ acc, float* __restrict__ out)
{
    __shared__ float smem[11788];
    float* enc_s    = smem;          // 512 (whole kernel)
    float* struct_s = smem + 512;    // 512 (until rel-mse)
    float* ping     = smem + 1024;   // 1024 (grad: dh1)
    float* pong     = smem + 2048;   // 1024
    float* ret1     = smem + 3072;   // 1024 (gen out; later inf out = out4)
    float* xa128    = smem + 4096;   // 512  (dec_gen_s; later final_s)
    float* out3_s   = smem + 4608;   // 1024 (grad: dh2)
    float* pvar_s   = smem + 5632;   // 512  (grad: dob)
    float* infs_s   = smem + 6144;   // 512
    float* ks       = smem + 6656;   // 512
    float* vs       = smem + 7168;   // 512
    float* h1       = smem + 7680;   // 1024
    float* h2       = smem + 8704;   // 1024
    float* part     = smem + 9728;   // 2048 (K-split partials)
    float* sse      = smem + 11776;  // 4
    float* red      = smem + 11780;  // 8
    const int t = threadIdx.x;
    const int row0 = blockIdx.x * 4;

    // P0: stage structural + encoded rows
    if (t < 256) {
        int r = (t >> 5) & 3, k4 = (t & 31) * 4;
        *(float4*)&struct_s[r*128 + k4] = *(const float4*)&structural[(size_t)(row0+r)*128 + k4];
        *(float4*)&enc_s[r*128 + k4]    = *(const float4*)&encoded[(size_t)(row0+r)*128 + k4];
    }
    __syncthreads();
    // P1: generative retrieve(structural, 0) -> ret1 (4x256)
    layer_ks4_n128(qw, nullptr, 128, struct_s, 128, ping, 128, 0, part, t);
    layer_ks2_n256(mW1, mb1, 128, ping, 128, pong, 1, nullptr, part, t);
    layer_ks2_n256(mW2, mb2, 256, pong, 256, ping, 1, nullptr, part, t);
    layer_ks4_n128(mW3, mb3, 256, ping, 256, pong, 128, 0, part, t);
    layer_ks2_n256(oW1, ob1, 128, pong, 128, ping, 1, nullptr, part, t);
    layer_ks2_n256(oW2, ob2, 256, ping, 256, pong, 1, nullptr, part, t);
    layer_ks2_n256(oW3, ob3, 256, pong, 256, ret1, 0, nullptr, part, t);
    // P1b: copy dec_gen_s -> xa128; relational MSE (out2 vs structural, x2)
    {
        const int r = t >> 7, c = t & 127;
        xa128[t] = ret1[r*256 + c];
        float d = out2[(size_t)(row0+r)*256 + c] - struct_s[r*128 + c];
        float relsum = d * d;
        block_mse_commit512(relsum, 2.f/131072.f, acc + 1, red, t);
    }
    __syncthreads();
    // P2: generative decoder MSE
    dec_mse512(ret1, sensory, row0, dec_w, dec_b, acc + 0, red, t);
    __syncthreads();
    // P3: retrieve #1 (dec_gen_s, encoded) -> out3_s
    layer_ks4_n128_dual(qw, xa128, enc_s, ping, part, t);
    layer_ks2_n256(mW1, mb1, 128, ping, 128, pong, 1, nullptr, part, t);
    layer_ks2_n256(mW2, mb2, 256, pong, 256, ping, 1, nullptr, part, t);
    layer_ks4_n128(mW3, mb3, 256, ping, 256, pong, 128, 0, part, t);
    layer_ks2_n256(oW1, ob1, 128, pong, 128, ping, 1, nullptr, part, t);
    layer_ks2_n256(oW2, ob2, 256, ping, 256, pong, 1, nullptr, part, t);
    layer_ks2_n256(oW3, ob3, 256, pong, 256, out3_s, 0, nullptr, part, t);
    // P4: sse per row; svar MLP -> pvar_s
    if (t < 256) {
        int r = (t >> 5) & 3, k4 = (t & 31) * 4;
        float4 ce = *(const float4*)&out3_s[r*256 + 128 + k4];
        float4 en = *(const float4*)&enc_s[r*128 + k4];
        float dx = ce.x-en.x, dy = ce.y-en.y, dz = ce.z-en.z, dw = ce.w-en.w;
        float ss = dx*dx + dy*dy + dz*dz + dw*dw;
        ss += __shfl_xor(ss, 16); ss += __shfl_xor(ss, 8); ss += __shfl_xor(ss, 4);
        ss += __shfl_xor(ss, 2);  ss += __shfl_xor(ss, 1);
        if ((t & 31) == 0) sse[r] = ss;
    }
    __syncthreads();
    {   // svar L1 (K=257, 2-way split over virtual k): g0=[0,128) corr_s; g1=[128,257)
        const int g = t >> 8;
        const int tt = t & 255;
        const int r = tt >> 6, c4 = (tt & 63) * 4;
        float4 a = make_float4(0.f,0.f,0.f,0.f);
        if (g == 0) {
            for (int k = 0; k < 128; ++k) {
                float4 w = *(const float4*)&sW1[(size_t)k*256 + c4];
                float xa = out3_s[r*256 + k];
                a.x=fmaf(w.x,xa,a.x); a.y=fmaf(w.y,xa,a.y); a.z=fmaf(w.z,xa,a.z); a.w=fmaf(w.w,xa,a.w);
            }
        } else {
            for (int k = 0; k < 128; ++k) {
                float4 w = *(const float4*)&sW1[(size_t)(128+k)*256 + c4];
                float xa = xa128[r*128 + k];
                a.x=fmaf(w.x,xa,a.x); a.y=fmaf(w.y,xa,a.y); a.z=fmaf(w.z,xa,a.z); a.w=fmaf(w.w,xa,a.w);
            }
            float4 w = *(const float4*)&sW1[(size_t)256*256 + c4];
            float xa = sse[r];
            a.x=fmaf(w.x,xa,a.x); a.y=fmaf(w.y,xa,a.y); a.z=fmaf(w.z,xa,a.z); a.w=fmaf(w.w,xa,a.w);
        }
        *(float4*)&part[g*1024 + tt*4] = a;
        __syncthreads();
        if (g == 0) {
            float4 p0 = *(const float4*)&part[tt*4];
            float4 p1 = *(const float4*)&part[1024 + tt*4];
            float4 b  = *(const float4*)&sb1[c4];
            float4 o;
            o.x = fmaxf(p0.x + p1.x + b.x, 0.f);
            o.y = fmaxf(p0.y + p1.y + b.y, 0.f);
            o.z = fmaxf(p0.z + p1.z + b.z, 0.f);
            o.w = fmaxf(p0.w + p1.w + b.w, 0.f);
            *(float4*)&ping[r*256 + c4] = o;
        }
        __syncthreads();
    }
    layer_ks2_n256(sW2, sb2, 256, ping, 256, pong, 1, nullptr, part, t);
    layer_ks4_n128(sW3, sb3, 256, pong, 256, pvar_s, 128, 0, part, t);
    // P5: infs + consistency loss
    {
        float ratio = ratio_p[0];
        const int r = t >> 7, j = t & 127;
        float dgs = xa128[t];
        float cs  = out3_s[r*256 + j];
        float pv  = pvar_s[t];
        float delta = (cs - dgs) * ratio * pv;
        infs_s[t] = dgs + delta;
        block_mse_commit512(delta * delta, 1.f/131072.f, acc + 2, red, t);
    }
    __syncthreads();
    // P6: retrieve #2 (inf_s, 0) -> ret1 (= out4)
    layer_ks4_n128(qw, nullptr, 128, infs_s, 128, ping, 128, 0, part, t);
    layer_ks2_n256(mW1, mb1, 128, ping, 128, pong, 1, nullptr, part, t);
    layer_ks2_n256(mW2, mb2, 256, pong, 256, ping, 1, nullptr, part, t);
    layer_ks4_n128(mW3, mb3, 256, ping, 256, pong, 128, 0, part, t);
    layer_ks2_n256(oW1, ob1, 128, pong, 128, ping, 1, nullptr, part, t);
    layer_ks2_n256(oW2, ob2, 256, ping, 256, pong, 1, nullptr, part, t);
    layer_ks2_n256(oW3, ob3, 256, pong, 256, ret1, 0, nullptr, part, t);
    // P7: inference decoder MSE
    dec_mse512(ret1, sensory, row0, dec_w, dec_b, acc + 3, red, t);
    __syncthreads();
    // P8: copy final_s -> xa128
    {
        const int r = t >> 7, c = t & 127;
        xa128[t] = ret1[r*256 + c];
    }
    __syncthreads();
    // P9: fast-weight grads
    float* dob = pvar_s;   // reuse (dead)
    float* dh2 = out3_s;   // reuse (dead)
    float* dh1 = ping;     // reuse (dead)
    layer_ks4_n128_dual(k_w, xa128, enc_s, ks, part, t);
    layer_ks4_n128_dual(v_w, xa128, enc_s, vs, part, t);
    layer_ks2_n256(mW1, mb1, 128, ks, 128, h1, 1, nullptr, part, t);
    layer_ks2_n256(mW2, mb2, 256, h1, 256, h2, 1, nullptr, part, t);
    layer_ks4_n128(mW3, mb3, 256, h2, 256, dob, 128, 0, part, t);
    dob[t] = (dob[t] - vs[t]) * 0.015625f;               // 2/128
    __syncthreads();
    layer_ks2_n256(T3, nullptr, 128, dob, 128, dh2, 0, h2, part, t);
    layer_ks2_n256(T2, nullptr, 256, dh2, 256, dh1, 0, h1, part, t);
    #pragma unroll
    for (int r = 0; r < 4; ++r) {
        const size_t row = row0 + r;
        {   // W1 grad: 128 x 256 (8 i-chunks of 16)
            const int c4 = (t & 63) * 4;
            const int i0 = (t >> 6) * 16;
            const float4 dv = *(const float4*)&dh1[r*256 + c4];
            float* p = out + OFF_W1 + row*32768;
            for (int i = i0; i < i0 + 16; ++i) {
                float kv = ks[r*128 + i];
                float4 o; o.x = kv*dv.x; o.y = kv*dv.y; o.z = kv*dv.z; o.w = kv*dv.w;
                *(float4*)&p[(size_t)i*256 + c4] = o;
            }
            if (t < 256) out[OFF_B1 + row*256 + t] = dh1[r*256 + t];
        }
        {   // W2 grad: 256 x 256 (8 i-chunks of 32)
            const int c4 = (t & 63) * 4;
            const int i0 = (t >> 6) * 32;
            const float4 dv = *(const float4*)&dh2[r*256 + c4];
            float* p = out + OFF_W2 + row*65536;
            for (int i = i0; i < i0 + 32; ++i) {
                float hv = h1[r*256 + i];
                float4 o; o.x = hv*dv.x; o.y = hv*dv.y; o.z = hv*dv.z; o.w = hv*dv.w;
                *(float4*)&p[(size_t)i*256 + c4] = o;
            }
            if (t < 256) out[OFF_B2 + row*256 + t] = dh2[r*256 + t];
        }
        {   // W3 grad: 256 x 128 (16 i-chunks of 16)
            const int c4 = (t & 31) * 4;
            const int i0 = (t >> 5) * 16;
            const float4 dv = *(const float4*)&dob[r*128 + c4];
            float* p = out + OFF_W3 + row*32768;
            for (int i = i0; i < i0 + 16; ++i) {
                float hv = h2[r*256 + i];
                float4 o; o.x = hv*dv.x; o.y = hv*dv.y; o.z = hv*dv.z; o.w = hv*dv.w;
                *(float4*)&p[(size_t)i*128 + c4] = o;
            }
            if (t < 128) out[OFF_B3 + row*128 + t] = dob[r*128 + t];
        }
    }
}

// ================= launch 5: total =================
__global__ void total_kernel(const float* acc, float* out) {
    if (threadIdx.x == 0)
        out[0] = acc[0] + acc[1] + acc[2] + acc[3];
}

// ================= host =================
extern "C" void kernel_launch(void* const* d_in, const int* in_sizes, int n_in,
                              void* d_out, int out_size, void* d_ws, size_t ws_size,
                              hipStream_t stream)
{
    const float* sensory     = (const float*)d_in[0];
    const float* actions     = (const float*)d_in[1];
    const float* init_hidden = (const float*)d_in[2];
    const float* tW1 = (const float*)d_in[3];  const float* tb1 = (const float*)d_in[4];
    const float* tW2 = (const float*)d_in[5];  const float* tb2 = (const float*)d_in[6];
    const float* tW3 = (const float*)d_in[7];  const float* tb3 = (const float*)d_in[8];
    const float* enc_w = (const float*)d_in[9];  const float* enc_b = (const float*)d_in[10];
    const float* dec_w = (const float*)d_in[11]; const float* dec_b = (const float*)d_in[12];
    const float* q_w = (const float*)d_in[13];
    const float* k_w = (const float*)d_in[14];
    const float* v_w = (const float*)d_in[15];
    const float* mW1 = (const float*)d_in[16]; const float* mb1 = (const float*)d_in[17];
    const float* mW2 = (const float*)d_in[18]; const float* mb2 = (const float*)d_in[19];
    const float* mW3 = (const float*)d_in[20]; const float* mb3 = (const float*)d_in[21];
    const float* oW1 = (const float*)d_in[22]; const float* ob1 = (const float*)d_in[23];
    const float* oW2 = (const float*)d_in[24]; const float* ob2 = (const float*)d_in[25];
    const float* oW3 = (const float*)d_in[26]; const float* ob3 = (const float*)d_in[27];
    const float* sW1 = (const float*)d_in[28]; const float* sb1 = (const float*)d_in[29];
    const float* sW2 = (const float*)d_in[30]; const float* sb2 = (const float*)d_in[31];
    const float* sW3 = (const float*)d_in[32]; const float* sb3 = (const float*)d_in[33];
    const float* ratio = (const float*)d_in[34];
    float* out = (float*)d_out;

    // workspace layout (floats) — footprint identical to the proven runs (19,234,832).
    float* Wsp = (float*)d_ws;
    float* acc   = Wsp;                         // 16 (loss accum 0..3)
    float* ALIAS = Wsp + 16;                    // 2,097,152 floats
    float* structural = ALIAS + 131072;         // 131072
    float* out2 = ALIAS + 524288;               // 262144
    float* tW3T = ALIAS;                        // full 2,097,152
    size_t off = 16 + 2097152;
    float* a2      = Wsp + off; off += 131072;
    float* encoded = Wsp + off; off += 131072;
    float* transT  = Wsp + off; off += 16777216;
    float* T2      = Wsp + off; off += 65536;
    float* T3      = Wsp + off; off += 32768;

    // 1. prep: tW3^T, T2, T3, acc zero, actions->a2 MLP, sensory encoder
    prep_kernel<<<801, 256, 0, stream>>>(tW3, mW2, mW3, actions, tW1, tb1, tW2, tb2,
                                         sensory, enc_w, enc_b, tW3T, T2, T3,
                                         acc, a2, encoded);

    // 2. transitions layer 3: K=128 GEMM -> transT (col-major per step)
    gemm_k128_kernel<<<dim3(32, 64), 256, 0, stream>>>(a2, 128, tW3T, tb3, transT, 16384);

    // 3. RNN scan (8 blocks) + relational retrieve (128 blocks, 512-thread layers)
    scanrel_kernel<<<136, 512, 0, stream>>>(transT, init_hidden, structural, encoded,
        q_w, mW1, mb1, mW2, mb2, mW3, mb3, oW1, ob1, oW2, ob2, oW3, ob3, out2);

    // 4. MEGA v2: 512-thread K-split row-local tail (8 waves/CU)
    mega_kernel<<<256, 512, 0, stream>>>(structural, encoded, out2, sensory, ratio,
        q_w, mW1, mb1, mW2, mb2, mW3, mb3, oW1, ob1, oW2, ob2, oW3, ob3,
        sW1, sb1, sW2, sb2, sW3, sb3, k_w, v_w, T2, T3, dec_w, dec_b, acc, out);

    // 5. total
    total_kernel<<<1, 64, 0, stream>>>(acc, out);
}

// Round 8
// 1451.750 us; speedup vs baseline: 1.2949x; 1.2949x over previous
//
#include <hip/hip_runtime.h>
#include <hip/hip_bf16.h>

// ---------------- output layout constants (floats) ----------------
constexpr size_t OFF_W1 = 1;
constexpr size_t OFF_B1 = OFF_W1 + (size_t)1024*32768;
constexpr size_t OFF_W2 = OFF_B1 + (size_t)1024*256;
constexpr size_t OFF_B2 = OFF_W2 + (size_t)1024*65536;
constexpr size_t OFF_W3 = OFF_B2 + (size_t)1024*256;
constexpr size_t OFF_B3 = OFF_W3 + (size_t)1024*32768;

// ================= 256-thread fused-MLP blocks (proven; prep/scanrel) =================
__device__ __forceinline__ void layer_n128(
    const float* __restrict__ W, const float* __restrict__ bias, int K,
    const float* __restrict__ x, int xs, float* __restrict__ y, int ys, int relu,
    int rows, int t)
{
    const int c4 = (t & 31) * 4;
    int r = t >> 5; if (rows == 4) r &= 3;
    float4 a = bias ? *(const float4*)&bias[c4] : make_float4(0.f,0.f,0.f,0.f);
    const float* xr = x + r * xs;
    for (int k = 0; k < K; ++k) {
        float4 w = *(const float4*)&W[(size_t)k*128 + c4];
        float xa = xr[k];
        a.x = fmaf(w.x, xa, a.x); a.y = fmaf(w.y, xa, a.y);
        a.z = fmaf(w.z, xa, a.z); a.w = fmaf(w.w, xa, a.w);
    }
    if (relu) {
        a.x=fmaxf(a.x,0.f); a.y=fmaxf(a.y,0.f); a.z=fmaxf(a.z,0.f); a.w=fmaxf(a.w,0.f);
    }
    *(float4*)&y[r*ys + c4] = a;
}

// N=256, 8 rows, 512 threads (1 row x 4 cols per thread) — scanrel
__device__ __forceinline__ void layer_n256_512(
    const float* __restrict__ W, const float* __restrict__ bias, int K,
    const float* __restrict__ x, int xs, float* __restrict__ y, int relu, int t)
{
    const int c4 = (t & 63) * 4;
    const int r = t >> 6;                 // 0..7
    float4 a = bias ? *(const float4*)&bias[c4] : make_float4(0.f,0.f,0.f,0.f);
    const float* xr = x + r * xs;
    for (int k = 0; k < K; ++k) {
        float4 w = *(const float4*)&W[(size_t)k*256 + c4];
        float xa = xr[k];
        a.x = fmaf(w.x, xa, a.x); a.y = fmaf(w.y, xa, a.y);
        a.z = fmaf(w.z, xa, a.z); a.w = fmaf(w.w, xa, a.w);
    }
    if (relu) {
        a.x=fmaxf(a.x,0.f); a.y=fmaxf(a.y,0.f); a.z=fmaxf(a.z,0.f); a.w=fmaxf(a.w,0.f);
    }
    *(float4*)&y[r*256 + c4] = a;
}

// ================= 2-row mega layer blocks (256 thr, no intra-layer barriers) ========
// N=256, 2 rows, float2/thread: r=t>>7, c2=(t&127)*2
__device__ __forceinline__ void layer2_n256(
    const float* __restrict__ W, const float* __restrict__ bias, int K,
    const float* __restrict__ x, int xs, float* __restrict__ y, int relu,
    const float* __restrict__ mask, int t)
{
    const int r = t >> 7;
    const int c2 = (t & 127) * 2;
    float2 a = bias ? *(const float2*)&bias[c2] : make_float2(0.f, 0.f);
    const float* xr = x + r * xs;
    for (int k = 0; k < K; ++k) {
        float2 w = *(const float2*)&W[(size_t)k*256 + c2];
        float xa = xr[k];
        a.x = fmaf(w.x, xa, a.x); a.y = fmaf(w.y, xa, a.y);
    }
    if (relu) { a.x = fmaxf(a.x, 0.f); a.y = fmaxf(a.y, 0.f); }
    if (mask) {
        float2 m = *(const float2*)&mask[r*256 + c2];
        a.x = (m.x > 0.f) ? a.x : 0.f; a.y = (m.y > 0.f) ? a.y : 0.f;
    }
    *(float2*)&y[r*256 + c2] = a;
}

// N=128, 2 rows, scalar/thread: r=t>>7, c=t&127
__device__ __forceinline__ void layer2_n128(
    const float* __restrict__ W, const float* __restrict__ bias, int K,
    const float* __restrict__ x, int xs, float* __restrict__ y, int ys, int relu, int t)
{
    const int r = t >> 7, c = t & 127;
    float a = bias ? bias[c] : 0.f;
    const float* xr = x + r * xs;
    for (int k = 0; k < K; ++k)
        a = fmaf(W[(size_t)k*128 + c], xr[k], a);
    if (relu) a = fmaxf(a, 0.f);
    y[r*ys + c] = a;
}

// dual-source N=128 proj: y = [xA|xB] @ W (W is 256x128), 2 rows, scalar/thread
__device__ __forceinline__ void layer2_n128_dual(
    const float* __restrict__ W,
    const float* __restrict__ xA, const float* __restrict__ xB,
    float* __restrict__ y, int t)
{
    const int r = t >> 7, c = t & 127;
    float a = 0.f;
    const float* xa_ = xA + r * 128;
    const float* xb_ = xB + r * 128;
    for (int k = 0; k < 128; ++k) a = fmaf(W[(size_t)k*128 + c], xa_[k], a);
    for (int k = 0; k < 128; ++k) a = fmaf(W[(size_t)(128+k)*128 + c], xb_[k], a);
    y[r*128 + c] = a;
}

// 256-thread block-sum commit (proven). Caller must sync before reusing red.
__device__ __forceinline__ void block_mse_commit(float s, float scale,
                                                 float* __restrict__ accum,
                                                 float* __restrict__ red, int t)
{
    #pragma unroll
    for (int off = 32; off > 0; off >>= 1) s += __shfl_down(s, off, 64);
    if ((t & 63) == 0) red[t >> 6] = s;
    __syncthreads();
    if (t == 0) atomicAdd(accum, (red[0]+red[1]+red[2]+red[3]) * scale);
}

// decoder-MSE, 2 rows (256 thr, float4): (ret[:,128:] @ dec_w + dec_b) vs sensory
__device__ __forceinline__ void dec_mse2(
    const float* __restrict__ ret,          // 2x256 LDS
    const float* __restrict__ sensory, int row0,
    const float* __restrict__ dec_w, const float* __restrict__ dec_b,
    float* __restrict__ accum, float* __restrict__ red, int t)
{
    const int c4 = (t & 127) * 4;
    const int rb = t >> 7;                  // 0..1
    float4 a = *(const float4*)&dec_b[c4];
    const float* x0 = ret + rb*256 + 128;
    for (int k = 0; k < 128; ++k) {
        float4 w = *(const float4*)&dec_w[(size_t)k*512 + c4];
        float xa = x0[k];
        a.x = fmaf(w.x, xa, a.x); a.y = fmaf(w.y, xa, a.y);
        a.z = fmaf(w.z, xa, a.z); a.w = fmaf(w.w, xa, a.w);
    }
    float4 s0 = *(const float4*)&sensory[(size_t)(row0+rb)*512 + c4];
    float dx = a.x-s0.x, dy = a.y-s0.y, dz = a.z-s0.z, dw = a.w-s0.w;
    float s = dx*dx + dy*dy + dz*dz + dw*dw;
    block_mse_commit(s, 1.f/524288.f, accum, red, t);
}

// ================= launch 1: prep (unchanged, proven) ====
__global__ __launch_bounds__(256) void prep_kernel(
    const float* __restrict__ tW3,
    const float* __restrict__ mW2, const float* __restrict__ mW3,
    const float* __restrict__ actions,
    const float* __restrict__ tW1, const float* __restrict__ tb1,
    const float* __restrict__ tW2, const float* __restrict__ tb2,
    const float* __restrict__ sensory,
    const float* __restrict__ enc_w, const float* __restrict__ enc_b,
    float* __restrict__ tW3T, float* __restrict__ T2, float* __restrict__ T3,
    float* __restrict__ acc, float* __restrict__ a2, float* __restrict__ encoded)
{
    __shared__ float smem[64*129];
    const int t = threadIdx.x;
    const int bid = blockIdx.x;
    if (bid < 256) {
        const int k = bid >> 1, i0 = (bid & 1) * 64;
        const size_t base = (size_t)k << 14;
        for (int l = t; l < 8192; l += 256) {
            int ii = l >> 7, jj = l & 127;
            smem[ii*129 + jj] = tW3[base + (size_t)(i0+ii)*128 + jj];
        }
        __syncthreads();
        for (int l = t; l < 8192; l += 256) {
            int jj = l >> 6, ii = l & 63;
            tW3T[base + (size_t)jj*128 + i0 + ii] = smem[ii*129 + jj];
        }
    } else if (bid < 512) {
        const int c = bid - 256;
        T2[(size_t)c*256 + t] = mW2[(size_t)t*256 + c];
    } else if (bid < 640) {
        const int c = bid - 512;
        T3[(size_t)c*256 + t] = mW3[(size_t)t*128 + c];
    } else if (bid == 640) {
        if (t < 16) acc[t] = 0.f;
    } else if (bid < 769) {
        float* bufAct = smem;            // 256
        float* ping   = smem + 256;      // 1024
        float* pong   = smem + 1280;     // 1024
        const int row0 = (bid - 641) * 8;
        if (t < 64) {
            int r = t >> 3, c4 = (t & 7) * 4;
            *(float4*)&bufAct[r*32 + c4] =
                *(const float4*)&actions[(size_t)(row0 + r)*32 + c4];
        }
        __syncthreads();
        layer_n128(tW1, tb1, 32, bufAct, 32, ping, 128, 1, 8, t);
        __syncthreads();
        layer_n128(tW2, tb2, 128, ping, 128, pong, 128, 1, 8, t);
        __syncthreads();
        {
            int r = t >> 5, c4 = (t & 31) * 4;
            *(float4*)&a2[(size_t)(row0 + r)*128 + c4] = *(const float4*)&pong[r*128 + c4];
        }
    } else {
        // encoder: sensory(1024x512) @ enc_w(512x128) + enc_b -> encoded
        const int q = bid - 769;              // 0..31
        const int m0 = (q & 15) * 64, n0 = (q >> 4) * 64;
        float (*As)[65] = (float(*)[65])smem;
        float (*Ws)[65] = (float(*)[65])(smem + 16*65);
        const int tx = t & 15, ty = t >> 4;
        float a4[4][4] = {};
        for (int k0 = 0; k0 < 512; k0 += 16) {
            for (int l = t; l < 1024; l += 256) {
                int mm = l >> 4, kk = l & 15;
                As[kk][mm] = sensory[(size_t)(m0+mm)*512 + k0 + kk];
            }
            for (int l = t; l < 1024; l += 256) {
                int kk = l >> 6, nn = l & 63;
                Ws[kk][nn] = enc_w[(size_t)(k0+kk)*128 + n0 + nn];
            }
            __syncthreads();
            #pragma unroll
            for (int kk = 0; kk < 16; ++kk) {
                float a[4], b[4];
                #pragma unroll
                for (int i=0;i<4;i++) a[i] = As[kk][ty*4+i];
                #pragma unroll
                for (int j=0;j<4;j++) b[j] = Ws[kk][tx*4+j];
                #pragma unroll
                for (int i=0;i<4;i++)
                    #pragma unroll
                    for (int j=0;j<4;j++)
                        a4[i][j] = fmaf(a[i], b[j], a4[i][j]);
            }
            __syncthreads();
        }
        #pragma unroll
        for (int i=0;i<4;i++){
            int gm = m0 + ty*4 + i;
            #pragma unroll
            for (int j=0;j<4;j++){
                int gn = n0 + tx*4 + j;
                encoded[(size_t)gm*128 + gn] = a4[i][j] + enc_b[gn];
            }
        }
    }
}

// ====== launch 2: K=128 GEMM, 32x256 tiles (unchanged, proven) ======
__global__ __launch_bounds__(256) void gemm_k128_kernel(
    const float* __restrict__ A, int lda, const float* __restrict__ W,
    const float* __restrict__ bias, float* __restrict__ C, int N)
{
    __shared__ float As[128*36];
    const int t = threadIdx.x;
    const int m0 = blockIdx.x * 32, n0 = blockIdx.y * 256;
    for (int l = t; l < 4096; l += 256) {
        int r = l >> 7, k = l & 127;
        As[k*36 + r] = A[(size_t)(m0 + r)*lda + k];
    }
    __syncthreads();
    const int c4 = (t & 63) * 4;
    const int r0 = (t >> 6) * 8;
    float4 bv;
    {   // bias stored transposed: bias[(n&127)*128 + (n>>7)]
        const int n = n0 + c4;
        const int j = n >> 7, i = n & 127;
        bv.x = bias[(size_t)(i+0)*128 + j];
        bv.y = bias[(size_t)(i+1)*128 + j];
        bv.z = bias[(size_t)(i+2)*128 + j];
        bv.w = bias[(size_t)(i+3)*128 + j];
    }
    float4 acc[8];
    #pragma unroll
    for (int i = 0; i < 8; ++i) acc[i] = bv;
    const float* Wp = W + (size_t)n0 + c4;
    #pragma unroll 4
    for (int k = 0; k < 128; ++k) {
        float4 w = *(const float4*)&Wp[(size_t)k*N];
        float a[8];
        *(float4*)&a[0] = *(const float4*)&As[k*36 + r0];
        *(float4*)&a[4] = *(const float4*)&As[k*36 + r0 + 4];
        #pragma unroll
        for (int i = 0; i < 8; ++i) {
            acc[i].x = fmaf(w.x, a[i], acc[i].x);
            acc[i].y = fmaf(w.y, a[i], acc[i].y);
            acc[i].z = fmaf(w.z, a[i], acc[i].z);
            acc[i].w = fmaf(w.w, a[i], acc[i].w);
        }
    }
    #pragma unroll
    for (int i = 0; i < 8; ++i)
        *(float4*)&C[(size_t)(m0 + r0 + i)*N + n0 + c4] = acc[i];
}

// ================= launch 3: scan (blocks 0..7) + relational retrieve (8..135) ======
// (unchanged from round-6, proven)
__global__ __launch_bounds__(512) void scanrel_kernel(
    const float* __restrict__ transT,
    const float* __restrict__ init_hidden,
    float* __restrict__ structural,
    const float* __restrict__ encoded,
    const float* __restrict__ qw,
    const float* __restrict__ mW1, const float* __restrict__ mb1,
    const float* __restrict__ mW2, const float* __restrict__ mb2,
    const float* __restrict__ mW3, const float* __restrict__ mb3,
    const float* __restrict__ oW1, const float* __restrict__ ob1,
    const float* __restrict__ oW2, const float* __restrict__ ob2,
    const float* __restrict__ oW3, const float* __restrict__ ob3,
    float* __restrict__ out2)
{
    __shared__ float smem[5120];
    const int tid = threadIdx.x;
    if (blockIdx.x < 8) {
        float* h  = smem;        // 128
        float* ws = smem + 128;  // 8
        const int b = blockIdx.x;
        const int j = tid >> 2, p = tid & 3;
        const int i0 = p * 32;

        if (tid < 32) {
            float4 v = *(const float4*)&init_hidden[tid*4];
            float ss = v.x*v.x + v.y*v.y + v.z*v.z + v.w*v.w;
            ss += __shfl_xor(ss, 16); ss += __shfl_xor(ss, 8); ss += __shfl_xor(ss, 4);
            ss += __shfl_xor(ss, 2);  ss += __shfl_xor(ss, 1);
            float inv = 1.f / fmaxf(sqrtf(ss), 1e-12f);
            v.x *= inv; v.y *= inv; v.z *= inv; v.w *= inv;
            *(float4*)&h[tid*4] = v;
        }
        __syncthreads();

        const size_t bbase = ((size_t)b) << 21;
        const int lane_off = j*128 + i0;
        float4 cur[8], nxt[8];
        {
            const float* T0 = transT + bbase + lane_off;
            #pragma unroll
            for (int r = 0; r < 8; ++r) cur[r] = *(const float4*)&T0[r*4];
        }
        for (int t = 0; t < 128; ++t) {
            const int tn = (t < 127) ? t + 1 : 127;
            const float* Tn = transT + bbase + ((size_t)tn << 14) + lane_off;
            #pragma unroll
            for (int r = 0; r < 8; ++r) nxt[r] = *(const float4*)&Tn[r*4];

            float4 a = make_float4(0.f, 0.f, 0.f, 0.f);
            #pragma unroll
            for (int r = 0; r < 8; ++r) {
                float4 hv = *(const float4*)&h[i0 + r*4];
                a.x = fmaf(hv.x, cur[r].x, a.x);
                a.y = fmaf(hv.y, cur[r].y, a.y);
                a.z = fmaf(hv.z, cur[r].z, a.z);
                a.w = fmaf(hv.w, cur[r].w, a.w);
            }
            float s = (a.x + a.y) + (a.z + a.w);
            s += __shfl_xor(s, 1);
            s += __shfl_xor(s, 2);
            float v = fmaxf(s, 0.f);
            float q = v * v;
            q += __shfl_xor(q, 4);  q += __shfl_xor(q, 8);
            q += __shfl_xor(q, 16); q += __shfl_xor(q, 32);
            if ((tid & 63) == 0) ws[tid >> 6] = q;
            __syncthreads();
            float ss = ((ws[0]+ws[1]) + (ws[2]+ws[3])) + ((ws[4]+ws[5]) + (ws[6]+ws[7]));
            float inv = 1.f / fmaxf(sqrtf(ss), 1e-12f);
            float hv = v * inv;
            __syncthreads();
            if (p == 0) h[j] = hv;
            else if (p == 1) structural[(((size_t)(b*128 + t)) << 7) + j] = hv;
            __syncthreads();
            #pragma unroll
            for (int r = 0; r < 8; ++r) cur[r] = nxt[r];
        }
    } else {
        float* bufB = smem;           // 1024
        float* ping = smem + 1024;    // 2048
        float* pong = smem + 3072;    // 2048
        const int row0 = (blockIdx.x - 8) * 8;
        const int t = tid;
        if (t < 256) {
            int r = t >> 5, k4 = (t & 31) * 4;
            *(float4*)&bufB[r*128 + k4] =
                *(const float4*)&encoded[(size_t)(row0 + r)*128 + k4];
        }
        __syncthreads();
        if (t < 256) layer_n128(qw + (size_t)128*128, nullptr, 128, bufB, 128, ping, 128, 0, 8, t);
        __syncthreads();
        layer_n256_512(mW1, mb1, 128, ping, 128, pong, 1, t);
        __syncthreads();
        layer_n256_512(mW2, mb2, 256, pong, 256, ping, 1, t);
        __syncthreads();
        if (t < 256) layer_n128(mW3, mb3, 256, ping, 256, pong, 128, 0, 8, t);
        __syncthreads();
        layer_n256_512(oW1, ob1, 128, pong, 128, ping, 1, t);
        __syncthreads();
        layer_n256_512(oW2, ob2, 256, ping, 256, pong, 1, t);
        __syncthreads();
        layer_n256_512(oW3, ob3, 256, pong, 256, ping, 0, t);
        __syncthreads();
        {
            int r = t >> 6, c = (t & 63) * 4;
            *(float4*)&out2[(size_t)(row0+r)*256 + c] = *(const float4*)&ping[r*256 + c];
        }
    }
}

// ====== launch 4: MEGA v3 — 512 blocks x 256 threads, 2-row groups ======
__global__ __launch_bounds__(256) void mega_kernel(
    const float* __restrict__ structural, const float* __restrict__ encoded,
    const float* __restrict__ out2, const float* __restrict__ sensory,
    const float* __restrict__ ratio_p,
    const float* __restrict__ qw,
    const float* __restrict__ mW1, const float* __restrict__ mb1,
    const float* __restrict__ mW2, const float* __restrict__ mb2,
    const float* __restrict__ mW3, const float* __restrict__ mb3,
    const float* __restrict__ oW1, const float* __restrict__ ob1,
    const float* __restrict__ oW2, const float* __restrict__ ob2,
    const float* __restrict__ oW3, const float* __restrict__ ob3,
    const float* __restrict__ sW1, const float* __restrict__ sb1,
    const float* __restrict__ sW2, const float* __restrict__ sb2,
    const float* __restrict__ sW3, const float* __restrict__ sb3,
    const float* __restrict__ k_w, const float* __restrict__ v_w,
    const float* __restrict__ T2, const float* __restrict__ T3,
    const float* __restrict__ dec_w, const float* __restrict__ dec_b,
    float* __restrict__ acc, float* __restrict__ out)
{
    __shared__ float smem[4880];
    float* enc_s    = smem;          // 256 (whole kernel)
    float* struct_s = smem + 256;    // 256 (until rel-mse)
    float* ping     = smem + 512;    // 512 (grad: dh1)
    float* pong     = smem + 1024;   // 512
    float* ret1     = smem + 1536;   // 512 (gen out; later inf out = out4)
    float* xa128    = smem + 2048;   // 256 (dec_gen_s; later final_s)
    float* out3_s   = smem + 2304;   // 512 (grad: dh2)
    float* pvar_s   = smem + 2816;   // 256 (grad: dob)
    float* infs_s   = smem + 3072;   // 256
    float* ks       = smem + 3328;   // 256
    float* vs       = smem + 3584;   // 256
    float* h1       = smem + 3840;   // 512
    float* h2       = smem + 4352;   // 512
    float* sse      = smem + 4864;   // 2
    float* wsse     = smem + 4866;   // 4
    float* red      = smem + 4872;   // 4
    const int t = threadIdx.x;
    const int row0 = blockIdx.x * 2;
    const int tr = t >> 7, tc = t & 127;    // element (row, col) for 2x128 ops

    // P0: stage structural + encoded rows (2 x 128 each)
    if (t < 64) {
        int r = t >> 5, k4 = (t & 31) * 4;
        *(float4*)&struct_s[r*128 + k4] = *(const float4*)&structural[(size_t)(row0+r)*128 + k4];
    } else if (t < 128) {
        int tt = t - 64;
        int r = tt >> 5, k4 = (tt & 31) * 4;
        *(float4*)&enc_s[r*128 + k4] = *(const float4*)&encoded[(size_t)(row0+r)*128 + k4];
    }
    __syncthreads();
    // P1: generative retrieve(structural, 0) -> ret1 (2x256)
    layer2_n128(qw, nullptr, 128, struct_s, 128, ping, 128, 0, t); __syncthreads();
    layer2_n256(mW1, mb1, 128, ping, 128, pong, 1, nullptr, t); __syncthreads();
    layer2_n256(mW2, mb2, 256, pong, 256, ping, 1, nullptr, t); __syncthreads();
    layer2_n128(mW3, mb3, 256, ping, 256, pong, 128, 0, t); __syncthreads();
    layer2_n256(oW1, ob1, 128, pong, 128, ping, 1, nullptr, t); __syncthreads();
    layer2_n256(oW2, ob2, 256, ping, 256, pong, 1, nullptr, t); __syncthreads();
    layer2_n256(oW3, ob3, 256, pong, 256, ret1, 0, nullptr, t); __syncthreads();
    // P1b: copy dec_gen_s -> xa128; relational MSE (out2 vs structural, x2)
    {
        xa128[t] = ret1[tr*256 + tc];
        float d = out2[(size_t)(row0+tr)*256 + tc] - struct_s[t];
        block_mse_commit(d * d, 2.f/131072.f, acc + 1, red, t);
    }
    __syncthreads();
    // P2: generative decoder MSE
    dec_mse2(ret1, sensory, row0, dec_w, dec_b, acc + 0, red, t);
    __syncthreads();
    // P3: retrieve #1 (dec_gen_s, encoded) -> out3_s
    layer2_n128_dual(qw, xa128, enc_s, ping, t); __syncthreads();
    layer2_n256(mW1, mb1, 128, ping, 128, pong, 1, nullptr, t); __syncthreads();
    layer2_n256(mW2, mb2, 256, pong, 256, ping, 1, nullptr, t); __syncthreads();
    layer2_n128(mW3, mb3, 256, ping, 256, pong, 128, 0, t); __syncthreads();
    layer2_n256(oW1, ob1, 128, pong, 128, ping, 1, nullptr, t); __syncthreads();
    layer2_n256(oW2, ob2, 256, ping, 256, pong, 1, nullptr, t); __syncthreads();
    layer2_n256(oW3, ob3, 256, pong, 256, out3_s, 0, nullptr, t); __syncthreads();
    // P4: sse per row (row r = waves 2r,2r+1), then svar MLP -> pvar_s
    {
        float ce = out3_s[tr*256 + 128 + tc];
        float en = enc_s[t];
        float d = ce - en;
        float s = d * d;
        #pragma unroll
        for (int off = 32; off > 0; off >>= 1) s += __shfl_down(s, off, 64);
        if ((t & 63) == 0) wsse[t >> 6] = s;
    }
    __syncthreads();
    if (t < 2) sse[t] = wsse[2*t] + wsse[2*t + 1];
    __syncthreads();
    {   // svar L1: [corr_s | dec_gen_s | sse] @ sW1 -> ping (2x256), relu
        const int r = t >> 7, c2 = (t & 127) * 2;
        float2 a = *(const float2*)&sb1[c2];
        for (int k = 0; k < 128; ++k) {
            float2 w = *(const float2*)&sW1[(size_t)k*256 + c2];
            float xa = out3_s[r*256 + k];
            a.x = fmaf(w.x, xa, a.x); a.y = fmaf(w.y, xa, a.y);
        }
        for (int k = 0; k < 128; ++k) {
            float2 w = *(const float2*)&sW1[(size_t)(128+k)*256 + c2];
            float xa = xa128[r*128 + k];
            a.x = fmaf(w.x, xa, a.x); a.y = fmaf(w.y, xa, a.y);
        }
        {
            float2 w = *(const float2*)&sW1[(size_t)256*256 + c2];
            float xa = sse[r];
            a.x = fmaf(w.x, xa, a.x); a.y = fmaf(w.y, xa, a.y);
        }
        a.x = fmaxf(a.x, 0.f); a.y = fmaxf(a.y, 0.f);
        *(float2*)&ping[r*256 + c2] = a;
    }
    __syncthreads();
    layer2_n256(sW2, sb2, 256, ping, 256, pong, 1, nullptr, t); __syncthreads();
    layer2_n128(sW3, sb3, 256, pong, 256, pvar_s, 128, 0, t); __syncthreads();
    // P5: infs + consistency loss
    {
        float ratio = ratio_p[0];
        float dgs = xa128[t];
        float cs  = out3_s[tr*256 + tc];
        float pv  = pvar_s[t];
        float delta = (cs - dgs) * ratio * pv;
        infs_s[t] = dgs + delta;
        block_mse_commit(delta * delta, 1.f/131072.f, acc + 2, red, t);
    }
    __syncthreads();
    // P6: retrieve #2 (inf_s, 0) -> ret1 (= out4)
    layer2_n128(qw, nullptr, 128, infs_s, 128, ping, 128, 0, t); __syncthreads();
    layer2_n256(mW1, mb1, 128, ping, 128, pong, 1, nullptr, t); __syncthreads();
    layer2_n256(mW2, mb2, 256, pong, 256, ping, 1, nullptr, t); __syncthreads();
    layer2_n128(mW3, mb3, 256, ping, 256, pong, 128, 0, t); __syncthreads();
    layer2_n256(oW1, ob1, 128, pong, 128, ping, 1, nullptr, t); __syncthreads();
    layer2_n256(oW2, ob2, 256, ping, 256, pong, 1, nullptr, t); __syncthreads();
    layer2_n256(oW3, ob3, 256, pong, 256, ret1, 0, nullptr, t); __syncthreads();
    // P7: inference decoder MSE
    dec_mse2(ret1, sensory, row0, dec_w, dec_b, acc + 3, red, t);
    __syncthreads();
    // P8: copy final_s -> xa128
    xa128[t] = ret1[tr*256 + tc];
    __syncthreads();
    // P9: fast-weight grads
    float* dob = pvar_s;   // reuse (dead)
    float* dh2 = out3_s;   // reuse (dead)
    float* dh1 = ping;     // reuse (dead)
    layer2_n128_dual(k_w, xa128, enc_s, ks, t);
    layer2_n128_dual(v_w, xa128, enc_s, vs, t);
    __syncthreads();
    layer2_n256(mW1, mb1, 128, ks, 128, h1, 1, nullptr, t); __syncthreads();
    layer2_n256(mW2, mb2, 256, h1, 256, h2, 1, nullptr, t); __syncthreads();
    layer2_n128(mW3, mb3, 256, h2, 256, dob, 128, 0, t); __syncthreads();
    dob[t] = (dob[t] - vs[t]) * 0.015625f;               // 2/128
    __syncthreads();
    layer2_n256(T3, nullptr, 128, dob, 128, dh2, 0, h2, t); __syncthreads();
    layer2_n256(T2, nullptr, 256, dh2, 256, dh1, 0, h1, t); __syncthreads();
    #pragma unroll
    for (int r = 0; r < 2; ++r) {
        const size_t row = row0 + r;
        {   // W1 grad: 128 x 256 (4 i-chunks of 32)
            const int c4 = (t & 63) * 4;
            const int i0 = (t >> 6) * 32;
            const float4 dv = *(const float4*)&dh1[r*256 + c4];
            float* p = out + OFF_W1 + row*32768;
            for (int i = i0; i < i0 + 32; ++i) {
                float kv = ks[r*128 + i];
                float4 o; o.x = kv*dv.x; o.y = kv*dv.y; o.z = kv*dv.z; o.w = kv*dv.w;
                *(float4*)&p[(size_t)i*256 + c4] = o;
            }
            out[OFF_B1 + row*256 + t] = dh1[r*256 + t];
        }
        {   // W2 grad: 256 x 256 (4 i-chunks of 64)
            const int c4 = (t & 63) * 4;
            const int i0 = (t >> 6) * 64;
            const float4 dv = *(const float4*)&dh2[r*256 + c4];
            float* p = out + OFF_W2 + row*65536;
            for (int i = i0; i < i0 + 64; ++i) {
                float hv = h1[r*256 + i];
                float4 o; o.x = hv*dv.x; o.y = hv*dv.y; o.z = hv*dv.z; o.w = hv*dv.w;
                *(float4*)&p[(size_t)i*256 + c4] = o;
            }
            out[OFF_B2 + row*256 + t] = dh2[r*256 + t];
        }
        {   // W3 grad: 256 x 128 (8 i-chunks of 32)
            const int c4 = (t & 31) * 4;
            const int i0 = (t >> 5) * 32;
            const float4 dv = *(const float4*)&dob[r*128 + c4];
            float* p = out + OFF_W3 + row*32768;
            for (int i = i0; i < i0 + 32; ++i) {
                float hv = h2[r*256 + i];
                float4 o; o.x = hv*dv.x; o.y = hv*dv.y; o.z = hv*dv.z; o.w = hv*dv.w;
                *(float4*)&p[(size_t)i*128 + c4] = o;
            }
            if (t < 128) out[OFF_B3 + row*128 + t] = dob[r*128 + t];
        }
    }
}

// ================= launch 5: total =================
__global__ void total_kernel(const float* acc, float* out) {
    if (threadIdx.x == 0)
        out[0] = acc[0] + acc[1] + acc[2] + acc[3];
}

// ================= host =================
extern "C" void kernel_launch(void* const* d_in, const int* in_sizes, int n_in,
                              void* d_out, int out_size, void* d_ws, size_t ws_size,
                              hipStream_t stream)
{
    const float* sensory     = (const float*)d_in[0];
    const float* actions     = (const float*)d_in[1];
    const float* init_hidden = (const float*)d_in[2];
    const float* tW1 = (const float*)d_in[3];  const float* tb1 = (const float*)d_in[4];
    const float* tW2 = (const float*)d_in[5];  const float* tb2 = (const float*)d_in[6];
    const float* tW3 = (const float*)d_in[7];  const float* tb3 = (const float*)d_in[8];
    const float* enc_w = (const float*)d_in[9];  const float* enc_b = (const float*)d_in[10];
    const float* dec_w = (const float*)d_in[11]; const float* dec_b = (const float*)d_in[12];
    const float* q_w = (const float*)d_in[13];
    const float* k_w = (const float*)d_in[14];
    const float* v_w = (const float*)d_in[15];
    const float* mW1 = (const float*)d_in[16]; const float* mb1 = (const float*)d_in[17];
    const float* mW2 = (const float*)d_in[18]; const float* mb2 = (const float*)d_in[19];
    const float* mW3 = (const float*)d_in[20]; const float* mb3 = (const float*)d_in[21];
    const float* oW1 = (const float*)d_in[22]; const float* ob1 = (const float*)d_in[23];
    const float* oW2 = (const float*)d_in[24]; const float* ob2 = (const float*)d_in[25];
    const float* oW3 = (const float*)d_in[26]; const float* ob3 = (const float*)d_in[27];
    const float* sW1 = (const float*)d_in[28]; const float* sb1 = (const float*)d_in[29];
    const float* sW2 = (const float*)d_in[30]; const float* sb2 = (const float*)d_in[31];
    const float* sW3 = (const float*)d_in[32]; const float* sb3 = (const float*)d_in[33];
    const float* ratio = (const float*)d_in[34];
    float* out = (float*)d_out;

    // workspace layout (floats) — footprint identical to the proven runs (19,234,832).
    float* Wsp = (float*)d_ws;
    float* acc   = Wsp;                         // 16 (loss accum 0..3)
    float* ALIAS = Wsp + 16;                    // 2,097,152 floats
    float* structural = ALIAS + 131072;         // 131072
    float* out2 = ALIAS + 524288;               // 262144
    float* tW3T = ALIAS;                        // full 2,097,152
    size_t off = 16 + 2097152;
    float* a2      = Wsp + off; off += 131072;
    float* encoded = Wsp + off; off += 131072;
    float* transT  = Wsp + off; off += 16777216;
    float* T2      = Wsp + off; off += 65536;
    float* T3      = Wsp + off; off += 32768;

    // 1. prep: tW3^T, T2, T3, acc zero, actions->a2 MLP, sensory encoder
    prep_kernel<<<801, 256, 0, stream>>>(tW3, mW2, mW3, actions, tW1, tb1, tW2, tb2,
                                         sensory, enc_w, enc_b, tW3T, T2, T3,
                                         acc, a2, encoded);

    // 2. transitions layer 3: K=128 GEMM -> transT (col-major per step)
    gemm_k128_kernel<<<dim3(32, 64), 256, 0, stream>>>(a2, 128, tW3T, tb3, transT, 16384);

    // 3. RNN scan (8 blocks) + relational retrieve (128 blocks)
    scanrel_kernel<<<136, 512, 0, stream>>>(transT, init_hidden, structural, encoded,
        q_w, mW1, mb1, mW2, mb2, mW3, mb3, oW1, ob1, oW2, ob2, oW3, ob3, out2);

    // 4. MEGA v3: 512 blocks x 2-row groups (2 blocks/CU, no spills)
    mega_kernel<<<512, 256, 0, stream>>>(structural, encoded, out2, sensory, ratio,
        q_w, mW1, mb1, mW2, mb2, mW3, mb3, oW1, ob1, oW2, ob2, oW3, ob3,
        sW1, sb1, sW2, sb2, sW3, sb3, k_w, v_w, T2, T3, dec_w, dec_b, acc, out);

    // 5. total
    total_kernel<<<1, 64, 0, stream>>>(acc, out);
}